// Round 1
// baseline (307.740 us; speedup 1.0000x reference)
//
#include <hip/hip_runtime.h>
#include <math.h>

// MEF-SSIM fused kernel for MI355X (gfx950)
// X: (1,3,1024,1024) f32, Ys: (6,3,1024,1024) f32, window: (3,1,11,11) f32 (Gaussian, separable)
// out: scalar f32 = mean over (C,H,W) of cs_map selected by argmax_k sigmaY_sq

#define HW 1024
#define CCH 3
#define KK 6
#define TW 32
#define TH 32
#define RAD 5
#define EXTW (TW + 2*RAD)   // 42
#define EXTH (TH + 2*RAD)   // 42
#define NBX (HW/TW)         // 32
#define NBY (HW/TH)         // 32
#define NBLK (NBX*NBY*CCH)  // 3072

#define C2F   9.0e-4f
#define EPSF  1.0e-8f
#define S2F   65025.0f      // 255^2

struct GW { float g[11]; };

__global__ __launch_bounds__(256) void mef_main(
    const float* __restrict__ X, const float* __restrict__ Ys,
    float* __restrict__ part, GW gw)
{
  __shared__ float sX[EXTH][EXTW];   // X tile + halo
  __shared__ float sY[EXTH][EXTW];   // current Y_k tile + halo
  __shared__ float hA[EXTH][TW];     // hconv(Y)  (or hconv(X) in X-phase)
  __shared__ float hB[EXTH][TW];     // hconv(Y^2) (or hconv(X^2))
  __shared__ float hC[EXTH][TW];     // hconv(X*Y)
  __shared__ float redf[12];

  const int tid = threadIdx.x;
  const int tx = tid & 31;
  const int ty = tid >> 5;
  const int bx = blockIdx.x, by = blockIdx.y, c = blockIdx.z;
  const int gx0 = bx*TW - RAD, gy0 = by*TH - RAD;
  const float* __restrict__ Xc = X + (size_t)c * (HW*HW);
  float vmax = 0.f;   // includes padding zeros; safe: predicate is (max <= 1)

  // ---- load X tile + halo ----
  for (int r = ty; r < EXTH; r += 8) {
    int gy = gy0 + r;
    bool rok = (unsigned)gy < (unsigned)HW;
    const float* row = Xc + (size_t)(rok ? gy : 0) * HW;
    for (int cc = tx; cc < EXTW; cc += 32) {
      int gx = gx0 + cc;
      float v = 0.f;
      if (rok && (unsigned)gx < (unsigned)HW) v = row[gx];
      sX[r][cc] = v;
      vmax = fmaxf(vmax, v);
    }
  }
  __syncthreads();

  // ---- X-phase: hconv of X, X^2 ----
  for (int e = tid; e < EXTH*TW; e += 256) {
    int r = e >> 5, cc = e & 31;
    float a = 0.f, b = 0.f;
    #pragma unroll
    for (int j = 0; j < 11; ++j) {
      float w = gw.g[j];
      float x = sX[r][cc + j];
      a += w * x;
      b += w * x * x;
    }
    hA[r][cc] = a; hB[r][cc] = b;
  }
  __syncthreads();

  float muX[4], cx2[4];
  #pragma unroll
  for (int i = 0; i < 4; ++i) {
    int y = ty + 8*i;
    float a = 0.f, b = 0.f;
    #pragma unroll
    for (int j = 0; j < 11; ++j) {
      float w = gw.g[j];
      a += w * hA[y+j][tx];
      b += w * hB[y+j][tx];
    }
    muX[i] = a; cx2[i] = b;
  }

  float bestS[4], bestXY[4];

  // ---- k loop over the 6 exposure images ----
  for (int k = 0; k < KK; ++k) {
    const float* __restrict__ Yc = Ys + ((size_t)k*CCH + c) * (HW*HW);
    // load Y tile + halo (safe vs. previous hconv: barrier after hconv(k-1)
    // guaranteed all sY reads done before we get here)
    for (int r = ty; r < EXTH; r += 8) {
      int gy = gy0 + r;
      bool rok = (unsigned)gy < (unsigned)HW;
      const float* row = Yc + (size_t)(rok ? gy : 0) * HW;
      for (int cc = tx; cc < EXTW; cc += 32) {
        int gx = gx0 + cc;
        float v = 0.f;
        if (rok && (unsigned)gx < (unsigned)HW) v = row[gx];
        sY[r][cc] = v;
        vmax = fmaxf(vmax, v);
      }
    }
    __syncthreads();   // sY loaded AND all vconv(k-1) reads of hA/hB/hC done

    // hconv of Y, Y^2, X*Y
    for (int e = tid; e < EXTH*TW; e += 256) {
      int r = e >> 5, cc = e & 31;
      float a = 0.f, b = 0.f, d = 0.f;
      #pragma unroll
      for (int j = 0; j < 11; ++j) {
        float w = gw.g[j];
        float yv = sY[r][cc + j];
        float xv = sX[r][cc + j];
        a += w * yv;
        b += w * yv * yv;
        d += w * xv * yv;
      }
      hA[r][cc] = a; hB[r][cc] = b; hC[r][cc] = d;
    }
    __syncthreads();

    // vconv + running argmax on sigmaY
    #pragma unroll
    for (int i = 0; i < 4; ++i) {
      int y = ty + 8*i;
      float a = 0.f, b = 0.f, d = 0.f;
      #pragma unroll
      for (int j = 0; j < 11; ++j) {
        float w = gw.g[j];
        a += w * hA[y+j][tx];
        b += w * hB[y+j][tx];
        d += w * hC[y+j][tx];
      }
      float sigY  = b - a * a;
      float sigXY = d - muX[i] * a;
      bool upd = (k == 0) || (sigY > bestS[i]);   // first-max semantics like argmax
      bestS[i]  = upd ? sigY  : bestS[i];
      bestXY[i] = upd ? sigXY : bestXY[i];
    }
  }

  // ---- epilogue: cs for both scale branches, block reduction ----
  float s1 = 0.f, s255 = 0.f;
  #pragma unroll
  for (int i = 0; i < 4; ++i) {
    float sigX = cx2[i] - muX[i] * muX[i];
    float num1 = 2.0f * bestXY[i] + C2F;
    float den1 = ((sigX + bestS[i]) + C2F) + EPSF;
    float cs1 = num1 / den1;
    float num2 = 2.0f * (S2F * bestXY[i]) + C2F;
    float den2 = ((S2F * sigX + S2F * bestS[i]) + C2F) + EPSF;
    float cs255 = num2 / den2;
    s1 += cs1;
    s255 += cs255;
  }

  #pragma unroll
  for (int off = 32; off > 0; off >>= 1) {
    s1   += __shfl_down(s1, off);
    s255 += __shfl_down(s255, off);
    vmax  = fmaxf(vmax, __shfl_down(vmax, off));
  }
  int w = tid >> 6;
  if ((tid & 63) == 0) { redf[w] = s1; redf[4+w] = s255; redf[8+w] = vmax; }
  __syncthreads();
  if (tid == 0) {
    float a = redf[0] + redf[1] + redf[2] + redf[3];
    float b = redf[4] + redf[5] + redf[6] + redf[7];
    float m = fmaxf(fmaxf(redf[8], redf[9]), fmaxf(redf[10], redf[11]));
    int bid = (c * NBY + by) * NBX + bx;
    part[bid*4 + 0] = a;
    part[bid*4 + 1] = b;
    part[bid*4 + 2] = m;
  }
}

__global__ __launch_bounds__(256) void mef_reduce(
    const float* __restrict__ part, float* __restrict__ out)
{
  int tid = threadIdx.x;
  double s1 = 0.0, s255 = 0.0;
  float m = 0.f;
  for (int i = tid; i < NBLK; i += 256) {
    s1   += (double)part[i*4 + 0];
    s255 += (double)part[i*4 + 1];
    m     = fmaxf(m, part[i*4 + 2]);
  }
  #pragma unroll
  for (int off = 32; off > 0; off >>= 1) {
    s1   += __shfl_down(s1, off);
    s255 += __shfl_down(s255, off);
    m     = fmaxf(m, __shfl_down(m, off));
  }
  __shared__ double l1[4], l2[4];
  __shared__ float lm[4];
  int w = tid >> 6;
  if ((tid & 63) == 0) { l1[w] = s1; l2[w] = s255; lm[w] = m; }
  __syncthreads();
  if (tid == 0) {
    double a = 0.0, b = 0.0; float mm = 0.f;
    for (int i = 0; i < 4; ++i) { a += l1[i]; b += l2[i]; mm = fmaxf(mm, lm[i]); }
    // scale=255 iff max(X)<=1 AND max(Ys)<=1  <=>  combined max <= 1
    out[0] = (float)(((mm <= 1.0f) ? b : a) / 3145728.0);
  }
}

extern "C" void kernel_launch(void* const* d_in, const int* in_sizes, int n_in,
                              void* d_out, int out_size, void* d_ws, size_t ws_size,
                              hipStream_t stream) {
  const float* X  = (const float*)d_in[0];
  const float* Ys = (const float*)d_in[1];
  // d_in[2] (window) unused: it is the analytic Gaussian (WS=11, sigma=1.5),
  // reconstructed here in double on the host exactly as the reference builds it.
  float* part = (float*)d_ws;     // NBLK*4 floats = 48 KB
  float* out  = (float*)d_out;

  GW gw;
  double gd[11], s = 0.0;
  for (int i = 0; i < 11; ++i) {
    double x = (double)(i - 5);
    gd[i] = exp(-(x*x) / (2.0 * 1.5 * 1.5));
    s += gd[i];
  }
  for (int i = 0; i < 11; ++i) gw.g[i] = (float)(gd[i] / s);

  dim3 grid(NBX, NBY, CCH);
  mef_main<<<grid, dim3(256), 0, stream>>>(X, Ys, part, gw);
  mef_reduce<<<1, dim3(256), 0, stream>>>(part, out);
}

// Round 5
// 285.571 us; speedup vs baseline: 1.0776x; 1.0776x over previous
//
#include <hip/hip_runtime.h>
#include <math.h>

// MEF-SSIM fused kernel for MI355X (gfx950) — R2: vectorized LDS traffic
// X: (1,3,1024,1024) f32, Ys: (6,3,1024,1024) f32, window: separable Gaussian 11x11
// out: scalar f32 = mean over (C,H,W) of cs_map selected by argmax_k sigmaY_sq

#define HW 1024
#define CCH 3
#define KK 6
#define TW 32
#define TH 32
#define RAD 5
#define EXTW (TW + 2*RAD)   // 42
#define EXTWP 44            // padded row stride (16B-aligned rows)
#define EXTH (TH + 2*RAD)   // 42
#define NBX (HW/TW)         // 32
#define NBY (HW/TH)         // 32
#define NBLK (NBX*NBY*CCH)  // 3072

#define C2F   9.0e-4f
#define EPSF  1.0e-8f
#define S2F   65025.0f      // 255^2

struct GW { float g[11]; };

__global__ __launch_bounds__(256) void mef_main(
    const float* __restrict__ X, const float* __restrict__ Ys,
    float* __restrict__ part, GW gw)
{
  __shared__ __align__(16) float sX[EXTH][EXTWP];  // X tile + halo
  __shared__ __align__(16) float sY[EXTH][EXTWP];  // current Y_k tile + halo
  __shared__ __align__(16) float hA[EXTH][TW];     // hconv(Y)  (or hconv(X))
  __shared__ __align__(16) float hB[EXTH][TW];     // hconv(Y^2) (or hconv(X^2))
  __shared__ __align__(16) float hC[EXTH][TW];     // hconv(X*Y)
  __shared__ float redf[12];

  const int tid = threadIdx.x;
  const int tx = tid & 31;
  const int ty = tid >> 5;
  const int bx = blockIdx.x, by = blockIdx.y, c = blockIdx.z;
  const int gx0 = bx*TW - RAD, gy0 = by*TH - RAD;
  const bool interior = (bx > 0) & (bx < NBX-1) & (by > 0) & (by < NBY-1);
  const float* __restrict__ Xc = X + (size_t)c * (HW*HW);
  float vmax = 0.f;   // padding zeros included; safe: predicate is (max <= 1)

  // ---- load X tile + halo ----
  if (interior) {
    for (int r = ty; r < EXTH; r += 8) {
      const float* row = Xc + (size_t)(gy0 + r) * HW + gx0;
      for (int cc = tx; cc < EXTW; cc += 32) {
        float v = row[cc];
        sX[r][cc] = v;
        vmax = fmaxf(vmax, v);
      }
    }
  } else {
    for (int r = ty; r < EXTH; r += 8) {
      int gy = gy0 + r;
      bool rok = (unsigned)gy < (unsigned)HW;
      const float* row = Xc + (size_t)(rok ? gy : 0) * HW;
      for (int cc = tx; cc < EXTW; cc += 32) {
        int gx = gx0 + cc;
        float v = 0.f;
        if (rok && (unsigned)gx < (unsigned)HW) v = row[gx];
        sX[r][cc] = v;
        vmax = fmaxf(vmax, v);
      }
    }
  }
  __syncthreads();

  // ---- X-phase hconv: 4-wide register tiles, float4 LDS reads ----
  for (int e = tid; e < EXTH*8; e += 256) {
    int r = e >> 3, cc0 = (e & 7) << 2;
    float4 q0 = *(const float4*)&sX[r][cc0];
    float4 q1 = *(const float4*)&sX[r][cc0+4];
    float4 q2 = *(const float4*)&sX[r][cc0+8];
    float4 q3 = *(const float4*)&sX[r][cc0+12];
    float xv[16] = {q0.x,q0.y,q0.z,q0.w, q1.x,q1.y,q1.z,q1.w,
                    q2.x,q2.y,q2.z,q2.w, q3.x,q3.y,q3.z,q3.w};
    float a[4] = {0,0,0,0}, b[4] = {0,0,0,0};
    #pragma unroll
    for (int j = 0; j < 11; ++j) {
      float w = gw.g[j];
      #pragma unroll
      for (int ww = 0; ww < 4; ++ww) {
        float x = xv[j+ww];
        a[ww] += w * x;
        b[ww] += w * x * x;
      }
    }
    *(float4*)&hA[r][cc0] = make_float4(a[0],a[1],a[2],a[3]);
    *(float4*)&hB[r][cc0] = make_float4(b[0],b[1],b[2],b[3]);
  }
  __syncthreads();

  // ---- X-phase vconv: each thread owns 4 CONSECUTIVE rows (taps shared) ----
  const int y0 = ty * 4;
  float muX[4], sigX[4];
  {
    float am[4] = {0,0,0,0}, bm[4] = {0,0,0,0};
    #pragma unroll
    for (int j = 0; j < 14; ++j) {
      float ha = hA[y0+j][tx];
      float hb = hB[y0+j][tx];
      #pragma unroll
      for (int i = 0; i < 4; ++i) {
        int t = j - i;
        if (t >= 0 && t <= 10) { am[i] += gw.g[t]*ha; bm[i] += gw.g[t]*hb; }
      }
    }
    #pragma unroll
    for (int i = 0; i < 4; ++i) { muX[i] = am[i]; sigX[i] = bm[i] - am[i]*am[i]; }
  }

  float bestS[4], bestXY[4];

  // ---- k loop over the 6 exposure images ----
  for (int k = 0; k < KK; ++k) {
    const float* __restrict__ Yc = Ys + ((size_t)k*CCH + c) * (HW*HW);
    if (interior) {
      for (int r = ty; r < EXTH; r += 8) {
        const float* row = Yc + (size_t)(gy0 + r) * HW + gx0;
        for (int cc = tx; cc < EXTW; cc += 32) {
          float v = row[cc];
          sY[r][cc] = v;
          vmax = fmaxf(vmax, v);
        }
      }
    } else {
      for (int r = ty; r < EXTH; r += 8) {
        int gy = gy0 + r;
        bool rok = (unsigned)gy < (unsigned)HW;
        const float* row = Yc + (size_t)(rok ? gy : 0) * HW;
        for (int cc = tx; cc < EXTW; cc += 32) {
          int gx = gx0 + cc;
          float v = 0.f;
          if (rok && (unsigned)gx < (unsigned)HW) v = row[gx];
          sY[r][cc] = v;
          vmax = fmaxf(vmax, v);
        }
      }
    }
    __syncthreads();   // sY ready AND prior vconv reads of hA/hB/hC complete

    // hconv of Y, Y^2, X*Y (4-wide register tiles)
    for (int e = tid; e < EXTH*8; e += 256) {
      int r = e >> 3, cc0 = (e & 7) << 2;
      float4 p0 = *(const float4*)&sY[r][cc0];
      float4 p1 = *(const float4*)&sY[r][cc0+4];
      float4 p2 = *(const float4*)&sY[r][cc0+8];
      float4 p3 = *(const float4*)&sY[r][cc0+12];
      float4 q0 = *(const float4*)&sX[r][cc0];
      float4 q1 = *(const float4*)&sX[r][cc0+4];
      float4 q2 = *(const float4*)&sX[r][cc0+8];
      float4 q3 = *(const float4*)&sX[r][cc0+12];
      float yv[16] = {p0.x,p0.y,p0.z,p0.w, p1.x,p1.y,p1.z,p1.w,
                      p2.x,p2.y,p2.z,p2.w, p3.x,p3.y,p3.z,p3.w};
      float xv[16] = {q0.x,q0.y,q0.z,q0.w, q1.x,q1.y,q1.z,q1.w,
                      q2.x,q2.y,q2.z,q2.w, q3.x,q3.y,q3.z,q3.w};
      float a[4] = {0,0,0,0}, b[4] = {0,0,0,0}, d[4] = {0,0,0,0};
      #pragma unroll
      for (int j = 0; j < 11; ++j) {
        float w = gw.g[j];
        #pragma unroll
        for (int ww = 0; ww < 4; ++ww) {
          float yy = yv[j+ww];
          a[ww] += w * yy;
          b[ww] += w * yy * yy;
          d[ww] += w * xv[j+ww] * yy;
        }
      }
      *(float4*)&hA[r][cc0] = make_float4(a[0],a[1],a[2],a[3]);
      *(float4*)&hB[r][cc0] = make_float4(b[0],b[1],b[2],b[3]);
      *(float4*)&hC[r][cc0] = make_float4(d[0],d[1],d[2],d[3]);
    }
    __syncthreads();

    // vconv + running argmax on sigmaY (4 consecutive rows/thread)
    {
      float a4[4] = {0,0,0,0}, b4[4] = {0,0,0,0}, d4[4] = {0,0,0,0};
      #pragma unroll
      for (int j = 0; j < 14; ++j) {
        float ha = hA[y0+j][tx];
        float hb = hB[y0+j][tx];
        float hc = hC[y0+j][tx];
        #pragma unroll
        for (int i = 0; i < 4; ++i) {
          int t = j - i;
          if (t >= 0 && t <= 10) {
            float w = gw.g[t];
            a4[i] += w*ha; b4[i] += w*hb; d4[i] += w*hc;
          }
        }
      }
      #pragma unroll
      for (int i = 0; i < 4; ++i) {
        float sigY  = b4[i] - a4[i]*a4[i];
        float sigXY = d4[i] - muX[i]*a4[i];
        bool upd = (k == 0) || (sigY > bestS[i]);  // first-max semantics
        bestS[i]  = upd ? sigY  : bestS[i];
        bestXY[i] = upd ? sigXY : bestXY[i];
      }
    }
  }

  // ---- epilogue: cs for both scale branches, block reduction ----
  float s1 = 0.f, s255 = 0.f;
  #pragma unroll
  for (int i = 0; i < 4; ++i) {
    float num1 = 2.0f * bestXY[i] + C2F;
    float den1 = ((sigX[i] + bestS[i]) + C2F) + EPSF;
    s1 += num1 / den1;
    float num2 = 2.0f * (S2F * bestXY[i]) + C2F;
    float den2 = ((S2F * sigX[i] + S2F * bestS[i]) + C2F) + EPSF;
    s255 += num2 / den2;
  }

  #pragma unroll
  for (int off = 32; off > 0; off >>= 1) {
    s1   += __shfl_down(s1, off);
    s255 += __shfl_down(s255, off);
    vmax  = fmaxf(vmax, __shfl_down(vmax, off));
  }
  int w = tid >> 6;
  if ((tid & 63) == 0) { redf[w] = s1; redf[4+w] = s255; redf[8+w] = vmax; }
  __syncthreads();
  if (tid == 0) {
    float a = redf[0] + redf[1] + redf[2] + redf[3];
    float b = redf[4] + redf[5] + redf[6] + redf[7];
    float m = fmaxf(fmaxf(redf[8], redf[9]), fmaxf(redf[10], redf[11]));
    int bid = (c * NBY + by) * NBX + bx;
    part[bid*4 + 0] = a;
    part[bid*4 + 1] = b;
    part[bid*4 + 2] = m;
  }
}

__global__ __launch_bounds__(256) void mef_reduce(
    const float* __restrict__ part, float* __restrict__ out)
{
  int tid = threadIdx.x;
  double s1 = 0.0, s255 = 0.0;
  float m = 0.f;
  for (int i = tid; i < NBLK; i += 256) {
    s1   += (double)part[i*4 + 0];
    s255 += (double)part[i*4 + 1];
    m     = fmaxf(m, part[i*4 + 2]);
  }
  #pragma unroll
  for (int off = 32; off > 0; off >>= 1) {
    s1   += __shfl_down(s1, off);
    s255 += __shfl_down(s255, off);
    m     = fmaxf(m, __shfl_down(m, off));
  }
  __shared__ double l1[4], l2[4];
  __shared__ float lm[4];
  int w = tid >> 6;
  if ((tid & 63) == 0) { l1[w] = s1; l2[w] = s255; lm[w] = m; }
  __syncthreads();
  if (tid == 0) {
    double a = 0.0, b = 0.0; float mm = 0.f;
    for (int i = 0; i < 4; ++i) { a += l1[i]; b += l2[i]; mm = fmaxf(mm, lm[i]); }
    out[0] = (float)(((mm <= 1.0f) ? b : a) / 3145728.0);
  }
}

extern "C" void kernel_launch(void* const* d_in, const int* in_sizes, int n_in,
                              void* d_out, int out_size, void* d_ws, size_t ws_size,
                              hipStream_t stream) {
  const float* X  = (const float*)d_in[0];
  const float* Ys = (const float*)d_in[1];
  // d_in[2] (window) unused: analytic Gaussian (WS=11, sigma=1.5) rebuilt on host.
  float* part = (float*)d_ws;
  float* out  = (float*)d_out;

  GW gw;
  double gd[11], s = 0.0;
  for (int i = 0; i < 11; ++i) {
    double x = (double)(i - 5);
    gd[i] = exp(-(x*x) / (2.0 * 1.5 * 1.5));
    s += gd[i];
  }
  for (int i = 0; i < 11; ++i) gw.g[i] = (float)(gd[i] / s);

  dim3 grid(NBX, NBY, CCH);
  mef_main<<<grid, dim3(256), 0, stream>>>(X, Ys, part, gw);
  mef_reduce<<<1, dim3(256), 0, stream>>>(part, out);
}

// Round 12
// 209.048 us; speedup vs baseline: 1.4721x; 1.3661x over previous
//
#include <hip/hip_runtime.h>
#include <math.h>

// MEF-SSIM fused kernel for MI355X (gfx950) — R4: R3 + bank-conflict-free h-buffers
// X: (1,3,1024,1024) f32, Ys: (6,3,1024,1024) f32, window: separable Gaussian 11x11
// out: scalar f32 = mean over (C,H,W) of cs_map selected by argmax_k sigmaY_sq

#define HW 1024
#define CCH 3
#define KK 6
#define TW 32
#define TH 32
#define RAD 5
#define EXTW 42             // TW + 2*RAD
#define EXTWP 44            // padded staging row stride (16B-aligned rows)
#define EXTH 42
#define HPW 36              // h-buffer row stride: mult of 4 (16B align), 36%32=4 spreads banks
#define NBX (HW/TW)         // 32
#define NBY (HW/TH)         // 32
#define NBLK (NBX*NBY*CCH)  // 3072
#define NITEM (EXTH*4)      // 168 hconv items, 8 outputs each

#define C2F   9.0e-4f
#define EPSF  1.0e-8f
#define S2F   65025.0f      // 255^2

struct GW { float g[11]; };

__global__ __launch_bounds__(256) void mef_main(
    const float* __restrict__ X, const float* __restrict__ Ys,
    float* __restrict__ part, GW gw)
{
  __shared__ __align__(16) float sY[EXTH][EXTWP];  // staging tile (X, then Y_k)
  __shared__ __align__(16) float hA[EXTH][HPW];    // hconv(Y) / hconv(X)
  __shared__ __align__(16) float hB[EXTH][HPW];    // hconv(Y^2) / hconv(X^2)
  __shared__ __align__(16) float hC[EXTH][HPW];    // hconv(X*Y)
  __shared__ float redf[12];

  const int tid = threadIdx.x;
  const int tx = tid & 31;
  const int ty = tid >> 5;
  const int bx = blockIdx.x, by = blockIdx.y, c = blockIdx.z;
  const int gx0 = bx*TW - RAD, gy0 = by*TH - RAD;
  const bool interior = (bx > 0) & (bx < NBX-1) & (by > 0) & (by < NBY-1);
  const bool hact = tid < NITEM;       // fixed item->thread map across all k
  const int ir  = tid >> 2;            // item row in [0,42)
  const int ic0 = (tid & 3) << 3;      // item col base {0,8,16,24}
  const int y0  = ty * 4;              // 4 consecutive output rows per thread

  const float* __restrict__ Xc = X + (size_t)c * (HW*HW);

  float vmax = 0.f;   // padding zeros included; safe: predicate is (max <= 1)
  float xw[20];       // X window for this thread's hconv item (valid if hact)
  float pf[12];       // prefetch registers (global -> reg -> LDS)

  // ---- prefetch-pattern load: global -> regs (slot (rr,ci): r=ty+8rr, c=tx+32ci)
  auto pf_load = [&](const float* __restrict__ src, float* p) {
    #pragma unroll
    for (int rr = 0; rr < 6; ++rr) {
      int r = ty + (rr << 3);
      int gy = gy0 + r;
      #pragma unroll
      for (int ci = 0; ci < 2; ++ci) {
        int cI = tx + (ci << 5);
        int gx = gx0 + cI;
        bool ok = (r < EXTH) & (cI < EXTW);
        if (!interior)
          ok = ok & ((unsigned)gy < (unsigned)HW) & ((unsigned)gx < (unsigned)HW);
        float v = 0.f;
        if (ok) v = src[(size_t)gy * HW + gx];
        p[rr*2 + ci] = v;
      }
    }
  };
  // ---- prefetch-pattern store: regs -> sY (+ vmax tracking; invalid slots are 0)
  auto pf_store = [&](const float* p) {
    #pragma unroll
    for (int rr = 0; rr < 6; ++rr) {
      int r = ty + (rr << 3);
      #pragma unroll
      for (int ci = 0; ci < 2; ++ci) {
        int cI = tx + (ci << 5);
        float v = p[rr*2 + ci];
        if ((r < EXTH) & (cI < EXTW)) sY[r][cI] = v;
        vmax = fmaxf(vmax, v);
      }
    }
  };

  // ================= X prologue =================
  pf_load(Xc, pf);
  pf_store(pf);              // stage X tile into sY
  __syncthreads();

  // X-hconv: load X window into registers ONCE (kept across all k), conv X, X^2
  if (hact) {
    float4 q0 = *(const float4*)&sY[ir][ic0];
    float4 q1 = *(const float4*)&sY[ir][ic0+4];
    float4 q2 = *(const float4*)&sY[ir][ic0+8];
    float4 q3 = *(const float4*)&sY[ir][ic0+12];
    float4 q4 = *(const float4*)&sY[ir][ic0+16];   // cols 42,43 garbage, never used
    xw[0]=q0.x; xw[1]=q0.y; xw[2]=q0.z; xw[3]=q0.w;
    xw[4]=q1.x; xw[5]=q1.y; xw[6]=q1.z; xw[7]=q1.w;
    xw[8]=q2.x; xw[9]=q2.y; xw[10]=q2.z; xw[11]=q2.w;
    xw[12]=q3.x; xw[13]=q3.y; xw[14]=q3.z; xw[15]=q3.w;
    xw[16]=q4.x; xw[17]=q4.y; xw[18]=q4.z; xw[19]=q4.w;
    float a8[8] = {0,0,0,0,0,0,0,0}, b8[8] = {0,0,0,0,0,0,0,0};
    #pragma unroll
    for (int j = 0; j < 11; ++j) {
      float w = gw.g[j];
      #pragma unroll
      for (int o = 0; o < 8; ++o) {
        float x = xw[j+o];
        a8[o] = fmaf(w, x, a8[o]);
        b8[o] = fmaf(w*x, x, b8[o]);
      }
    }
    *(float4*)&hA[ir][ic0]   = make_float4(a8[0],a8[1],a8[2],a8[3]);
    *(float4*)&hA[ir][ic0+4] = make_float4(a8[4],a8[5],a8[6],a8[7]);
    *(float4*)&hB[ir][ic0]   = make_float4(b8[0],b8[1],b8[2],b8[3]);
    *(float4*)&hB[ir][ic0+4] = make_float4(b8[4],b8[5],b8[6],b8[7]);
  }
  __syncthreads();

  // Phase B_X: issue Y0 prefetch EARLY, X-vconv under it, then stage Y0
  pf_load(Ys + (size_t)c * (HW*HW), pf);
  float muX[4], sigX[4];
  {
    float am[4] = {0,0,0,0}, bm[4] = {0,0,0,0};
    #pragma unroll
    for (int j = 0; j < 14; ++j) {
      float ha = hA[y0+j][tx];
      float hb = hB[y0+j][tx];
      #pragma unroll
      for (int i = 0; i < 4; ++i) {
        int t = j - i;                      // compile-time per (j,i)
        if (t >= 0 && t <= 10) {
          am[i] = fmaf(gw.g[t], ha, am[i]);
          bm[i] = fmaf(gw.g[t], hb, bm[i]);
        }
      }
    }
    #pragma unroll
    for (int i = 0; i < 4; ++i) { muX[i] = am[i]; sigX[i] = bm[i] - am[i]*am[i]; }
  }
  pf_store(pf);              // sY <- Y0 (X-hconv sY reads fenced by prior barrier)
  __syncthreads();

  float bestS[4], bestXY[4];

  // ================= k loop =================
  for (int k = 0; k < KK; ++k) {
    // ---- Phase A: hconv(k) of Y, Y^2, X*Y (X from registers) ----
    if (hact) {
      float yw[20];
      float4 p0 = *(const float4*)&sY[ir][ic0];
      float4 p1 = *(const float4*)&sY[ir][ic0+4];
      float4 p2 = *(const float4*)&sY[ir][ic0+8];
      float4 p3 = *(const float4*)&sY[ir][ic0+12];
      float4 p4 = *(const float4*)&sY[ir][ic0+16];
      yw[0]=p0.x; yw[1]=p0.y; yw[2]=p0.z; yw[3]=p0.w;
      yw[4]=p1.x; yw[5]=p1.y; yw[6]=p1.z; yw[7]=p1.w;
      yw[8]=p2.x; yw[9]=p2.y; yw[10]=p2.z; yw[11]=p2.w;
      yw[12]=p3.x; yw[13]=p3.y; yw[14]=p3.z; yw[15]=p3.w;
      yw[16]=p4.x; yw[17]=p4.y; yw[18]=p4.z; yw[19]=p4.w;
      float a8[8] = {0,0,0,0,0,0,0,0};
      float b8[8] = {0,0,0,0,0,0,0,0};
      float d8[8] = {0,0,0,0,0,0,0,0};
      #pragma unroll
      for (int j = 0; j < 11; ++j) {
        float w = gw.g[j];
        #pragma unroll
        for (int o = 0; o < 8; ++o) {
          float y  = yw[j+o];
          float wy = w * y;
          a8[o] = fmaf(w, y, a8[o]);
          b8[o] = fmaf(wy, y, b8[o]);
          d8[o] = fmaf(wy, xw[j+o], d8[o]);
        }
      }
      *(float4*)&hA[ir][ic0]   = make_float4(a8[0],a8[1],a8[2],a8[3]);
      *(float4*)&hA[ir][ic0+4] = make_float4(a8[4],a8[5],a8[6],a8[7]);
      *(float4*)&hB[ir][ic0]   = make_float4(b8[0],b8[1],b8[2],b8[3]);
      *(float4*)&hB[ir][ic0+4] = make_float4(b8[4],b8[5],b8[6],b8[7]);
      *(float4*)&hC[ir][ic0]   = make_float4(d8[0],d8[1],d8[2],d8[3]);
      *(float4*)&hC[ir][ic0+4] = make_float4(d8[4],d8[5],d8[6],d8[7]);
    }
    __syncthreads();

    // ---- Phase B: prefetch Y(k+1) first (latency hides under vconv) ----
    if (k < KK-1) {
      const float* __restrict__ Yn = Ys + ((size_t)(k+1)*CCH + c) * (HW*HW);
      pf_load(Yn, pf);
    }
    // vconv(k) + running argmax on sigmaY
    {
      float a4[4] = {0,0,0,0}, b4[4] = {0,0,0,0}, d4[4] = {0,0,0,0};
      #pragma unroll
      for (int j = 0; j < 14; ++j) {
        float ha = hA[y0+j][tx];
        float hb = hB[y0+j][tx];
        float hc = hC[y0+j][tx];
        #pragma unroll
        for (int i = 0; i < 4; ++i) {
          int t = j - i;
          if (t >= 0 && t <= 10) {
            float w = gw.g[t];
            a4[i] = fmaf(w, ha, a4[i]);
            b4[i] = fmaf(w, hb, b4[i]);
            d4[i] = fmaf(w, hc, d4[i]);
          }
        }
      }
      #pragma unroll
      for (int i = 0; i < 4; ++i) {
        float sigY  = b4[i] - a4[i]*a4[i];
        float sigXY = d4[i] - muX[i]*a4[i];
        bool upd = (k == 0) || (sigY > bestS[i]);  // first-max semantics
        bestS[i]  = upd ? sigY  : bestS[i];
        bestXY[i] = upd ? sigXY : bestXY[i];
      }
    }
    if (k < KK-1) {
      pf_store(pf);          // sY <- Y(k+1); phase-A reads fenced by A/B barrier
      __syncthreads();
    }
  }

  // ---- epilogue: cs for both scale branches, block reduction ----
  float s1 = 0.f, s255 = 0.f;
  #pragma unroll
  for (int i = 0; i < 4; ++i) {
    float num1 = 2.0f * bestXY[i] + C2F;
    float den1 = ((sigX[i] + bestS[i]) + C2F) + EPSF;
    s1 += num1 / den1;
    float num2 = 2.0f * (S2F * bestXY[i]) + C2F;
    float den2 = ((S2F * sigX[i] + S2F * bestS[i]) + C2F) + EPSF;
    s255 += num2 / den2;
  }

  #pragma unroll
  for (int off = 32; off > 0; off >>= 1) {
    s1   += __shfl_down(s1, off);
    s255 += __shfl_down(s255, off);
    vmax  = fmaxf(vmax, __shfl_down(vmax, off));
  }
  int w = tid >> 6;
  if ((tid & 63) == 0) { redf[w] = s1; redf[4+w] = s255; redf[8+w] = vmax; }
  __syncthreads();
  if (tid == 0) {
    float a = redf[0] + redf[1] + redf[2] + redf[3];
    float b = redf[4] + redf[5] + redf[6] + redf[7];
    float m = fmaxf(fmaxf(redf[8], redf[9]), fmaxf(redf[10], redf[11]));
    int bid = (c * NBY + by) * NBX + bx;
    part[bid*4 + 0] = a;
    part[bid*4 + 1] = b;
    part[bid*4 + 2] = m;
  }
}

__global__ __launch_bounds__(256) void mef_reduce(
    const float* __restrict__ part, float* __restrict__ out)
{
  int tid = threadIdx.x;
  double s1 = 0.0, s255 = 0.0;
  float m = 0.f;
  for (int i = tid; i < NBLK; i += 256) {
    s1   += (double)part[i*4 + 0];
    s255 += (double)part[i*4 + 1];
    m     = fmaxf(m, part[i*4 + 2]);
  }
  #pragma unroll
  for (int off = 32; off > 0; off >>= 1) {
    s1   += __shfl_down(s1, off);
    s255 += __shfl_down(s255, off);
    m     = fmaxf(m, __shfl_down(m, off));
  }
  __shared__ double l1[4], l2[4];
  __shared__ float lm[4];
  int w = tid >> 6;
  if ((tid & 63) == 0) { l1[w] = s1; l2[w] = s255; lm[w] = m; }
  __syncthreads();
  if (tid == 0) {
    double a = 0.0, b = 0.0; float mm = 0.f;
    for (int i = 0; i < 4; ++i) { a += l1[i]; b += l2[i]; mm = fmaxf(mm, lm[i]); }
    out[0] = (float)(((mm <= 1.0f) ? b : a) / 3145728.0);
  }
}

extern "C" void kernel_launch(void* const* d_in, const int* in_sizes, int n_in,
                              void* d_out, int out_size, void* d_ws, size_t ws_size,
                              hipStream_t stream) {
  const float* X  = (const float*)d_in[0];
  const float* Ys = (const float*)d_in[1];
  // d_in[2] (window) unused: analytic Gaussian (WS=11, sigma=1.5) rebuilt on host.
  float* part = (float*)d_ws;
  float* out  = (float*)d_out;

  GW gw;
  double gd[11], s = 0.0;
  for (int i = 0; i < 11; ++i) {
    double x = (double)(i - 5);
    gd[i] = exp(-(x*x) / (2.0 * 1.5 * 1.5));
    s += gd[i];
  }
  for (int i = 0; i < 11; ++i) gw.g[i] = (float)(gd[i] / s);

  dim3 grid(NBX, NBY, CCH);
  mef_main<<<grid, dim3(256), 0, stream>>>(X, Ys, part, gw);
  mef_reduce<<<1, dim3(256), 0, stream>>>(part, out);
}

// Round 14
// 203.833 us; speedup vs baseline: 1.5098x; 1.0256x over previous
//
#include <hip/hip_runtime.h>
#include <math.h>

// MEF-SSIM fused kernel for MI355X (gfx950) — R5: R4 + hoisted prefetch addressing
// X: (1,3,1024,1024) f32, Ys: (6,3,1024,1024) f32, window: separable Gaussian 11x11
// out: scalar f32 = mean over (C,H,W) of cs_map selected by argmax_k sigmaY_sq

#define HW 1024
#define CCH 3
#define KK 6
#define TW 32
#define TH 32
#define RAD 5
#define EXTW 42             // TW + 2*RAD
#define EXTWP 44            // padded staging row stride (16B-aligned rows)
#define EXTH 42
#define HPW 36              // h-buffer row stride: mult of 4, 36%32=4 spreads banks
#define NBX (HW/TW)         // 32
#define NBY (HW/TH)         // 32
#define NBLK (NBX*NBY*CCH)  // 3072
#define NITEM (EXTH*4)      // 168 hconv items, 8 outputs each

#define C2F   9.0e-4f
#define EPSF  1.0e-8f
#define S2F   65025.0f      // 255^2

struct GW { float g[11]; };

__global__ __launch_bounds__(256) void mef_main(
    const float* __restrict__ X, const float* __restrict__ Ys,
    float* __restrict__ part, GW gw)
{
  __shared__ __align__(16) float sY[EXTH][EXTWP];  // staging tile (X, then Y_k)
  __shared__ __align__(16) float hA[EXTH][HPW];    // hconv(Y) / hconv(X)
  __shared__ __align__(16) float hB[EXTH][HPW];    // hconv(Y^2) / hconv(X^2)
  __shared__ __align__(16) float hC[EXTH][HPW];    // hconv(X*Y)
  __shared__ float redf[12];

  const int tid = threadIdx.x;
  const int tx = tid & 31;
  const int ty = tid >> 5;
  const int bx = blockIdx.x, by = blockIdx.y, c = blockIdx.z;
  const int gx0 = bx*TW - RAD, gy0 = by*TH - RAD;
  const bool hact = tid < NITEM;       // fixed item->thread map across all k
  const int ir  = tid >> 2;            // item row in [0,42)
  const int ic0 = (tid & 3) << 3;      // item col base {0,8,16,24}
  const int y0  = ty * 4;              // 4 consecutive output rows per thread

  const float* __restrict__ Xc = X + (size_t)c * (HW*HW);

  float vmax = 0.f;   // padding zeros included; safe: predicate is (max <= 1)
  float xw[20];       // X window for this thread's hconv item (valid if hact)
  float pf[12];       // prefetch registers (global -> reg -> LDS)

  // ---- hoisted prefetch addressing: per-slot clamped index + validity masks ----
  // slot (rr,ci): tile coords r = ty+8*rr, cI = tx+32*ci
  int idx[12];
  unsigned tvm = 0;   // tile-valid (slot maps into EXTH x EXTW)
  unsigned ivm = 0;   // image-valid (value is real, not zero-padding)
  #pragma unroll
  for (int rr = 0; rr < 6; ++rr) {
    int r = ty + (rr << 3);
    int gy = gy0 + r;
    #pragma unroll
    for (int ci = 0; ci < 2; ++ci) {
      int s = rr*2 + ci;
      int cI = tx + (ci << 5);
      int gx = gx0 + cI;
      bool tv = (r < EXTH) & (cI < EXTW);
      bool iv = tv & ((unsigned)gy < (unsigned)HW) & ((unsigned)gx < (unsigned)HW);
      idx[s] = iv ? (gy * HW + gx) : 0;   // clamped: OOB slots read plane[0], masked later
      tvm |= (unsigned)tv << s;
      ivm |= (unsigned)iv << s;
    }
  }

  // pure loads — no VALU prelude, no exec masking; issue early, mask at store
  auto pf_load = [&](const float* __restrict__ plane, float* p) {
    #pragma unroll
    for (int s = 0; s < 12; ++s) p[s] = plane[idx[s]];
  };
  auto pf_store = [&](const float* p) {
    #pragma unroll
    for (int rr = 0; rr < 6; ++rr) {
      int r = ty + (rr << 3);
      #pragma unroll
      for (int ci = 0; ci < 2; ++ci) {
        int s = rr*2 + ci;
        int cI = tx + (ci << 5);
        float v = ((ivm >> s) & 1u) ? p[s] : 0.f;
        if ((tvm >> s) & 1u) sY[r][cI] = v;
        vmax = fmaxf(vmax, v);
      }
    }
  };

  // ================= X prologue =================
  pf_load(Xc, pf);
  pf_store(pf);              // stage X tile into sY
  __syncthreads();

  // X-hconv: load X window into registers ONCE (kept across all k), conv X, X^2
  if (hact) {
    float4 q0 = *(const float4*)&sY[ir][ic0];
    float4 q1 = *(const float4*)&sY[ir][ic0+4];
    float4 q2 = *(const float4*)&sY[ir][ic0+8];
    float4 q3 = *(const float4*)&sY[ir][ic0+12];
    float4 q4 = *(const float4*)&sY[ir][ic0+16];   // cols 42,43 garbage, never used
    xw[0]=q0.x; xw[1]=q0.y; xw[2]=q0.z; xw[3]=q0.w;
    xw[4]=q1.x; xw[5]=q1.y; xw[6]=q1.z; xw[7]=q1.w;
    xw[8]=q2.x; xw[9]=q2.y; xw[10]=q2.z; xw[11]=q2.w;
    xw[12]=q3.x; xw[13]=q3.y; xw[14]=q3.z; xw[15]=q3.w;
    xw[16]=q4.x; xw[17]=q4.y; xw[18]=q4.z; xw[19]=q4.w;
    float a8[8] = {0,0,0,0,0,0,0,0}, b8[8] = {0,0,0,0,0,0,0,0};
    #pragma unroll
    for (int j = 0; j < 11; ++j) {
      float w = gw.g[j];
      #pragma unroll
      for (int o = 0; o < 8; ++o) {
        float x = xw[j+o];
        a8[o] = fmaf(w, x, a8[o]);
        b8[o] = fmaf(w*x, x, b8[o]);
      }
    }
    *(float4*)&hA[ir][ic0]   = make_float4(a8[0],a8[1],a8[2],a8[3]);
    *(float4*)&hA[ir][ic0+4] = make_float4(a8[4],a8[5],a8[6],a8[7]);
    *(float4*)&hB[ir][ic0]   = make_float4(b8[0],b8[1],b8[2],b8[3]);
    *(float4*)&hB[ir][ic0+4] = make_float4(b8[4],b8[5],b8[6],b8[7]);
  }
  __syncthreads();

  // Phase B_X: issue Y0 prefetch EARLY, X-vconv under it, then stage Y0
  pf_load(Ys + (size_t)c * (HW*HW), pf);
  float muX[4], sigX[4];
  {
    float am[4] = {0,0,0,0}, bm[4] = {0,0,0,0};
    #pragma unroll
    for (int j = 0; j < 14; ++j) {
      float ha = hA[y0+j][tx];
      float hb = hB[y0+j][tx];
      #pragma unroll
      for (int i = 0; i < 4; ++i) {
        int t = j - i;                      // compile-time per (j,i)
        if (t >= 0 && t <= 10) {
          am[i] = fmaf(gw.g[t], ha, am[i]);
          bm[i] = fmaf(gw.g[t], hb, bm[i]);
        }
      }
    }
    #pragma unroll
    for (int i = 0; i < 4; ++i) { muX[i] = am[i]; sigX[i] = bm[i] - am[i]*am[i]; }
  }
  pf_store(pf);              // sY <- Y0 (X-hconv sY reads fenced by prior barrier)
  __syncthreads();

  float bestS[4], bestXY[4];

  // ================= k loop =================
  for (int k = 0; k < KK; ++k) {
    // ---- Phase A: hconv(k) of Y, Y^2, X*Y (X from registers) ----
    if (hact) {
      float yw[20];
      float4 p0 = *(const float4*)&sY[ir][ic0];
      float4 p1 = *(const float4*)&sY[ir][ic0+4];
      float4 p2 = *(const float4*)&sY[ir][ic0+8];
      float4 p3 = *(const float4*)&sY[ir][ic0+12];
      float4 p4 = *(const float4*)&sY[ir][ic0+16];
      yw[0]=p0.x; yw[1]=p0.y; yw[2]=p0.z; yw[3]=p0.w;
      yw[4]=p1.x; yw[5]=p1.y; yw[6]=p1.z; yw[7]=p1.w;
      yw[8]=p2.x; yw[9]=p2.y; yw[10]=p2.z; yw[11]=p2.w;
      yw[12]=p3.x; yw[13]=p3.y; yw[14]=p3.z; yw[15]=p3.w;
      yw[16]=p4.x; yw[17]=p4.y; yw[18]=p4.z; yw[19]=p4.w;
      float a8[8] = {0,0,0,0,0,0,0,0};
      float b8[8] = {0,0,0,0,0,0,0,0};
      float d8[8] = {0,0,0,0,0,0,0,0};
      #pragma unroll
      for (int j = 0; j < 11; ++j) {
        float w = gw.g[j];
        #pragma unroll
        for (int o = 0; o < 8; ++o) {
          float y  = yw[j+o];
          float wy = w * y;
          a8[o] = fmaf(w, y, a8[o]);
          b8[o] = fmaf(wy, y, b8[o]);
          d8[o] = fmaf(wy, xw[j+o], d8[o]);
        }
      }
      *(float4*)&hA[ir][ic0]   = make_float4(a8[0],a8[1],a8[2],a8[3]);
      *(float4*)&hA[ir][ic0+4] = make_float4(a8[4],a8[5],a8[6],a8[7]);
      *(float4*)&hB[ir][ic0]   = make_float4(b8[0],b8[1],b8[2],b8[3]);
      *(float4*)&hB[ir][ic0+4] = make_float4(b8[4],b8[5],b8[6],b8[7]);
      *(float4*)&hC[ir][ic0]   = make_float4(d8[0],d8[1],d8[2],d8[3]);
      *(float4*)&hC[ir][ic0+4] = make_float4(d8[4],d8[5],d8[6],d8[7]);
    }
    __syncthreads();

    // ---- Phase B: prefetch Y(k+1) first (latency hides under vconv) ----
    if (k < KK-1) {
      const float* __restrict__ Yn = Ys + ((size_t)(k+1)*CCH + c) * (HW*HW);
      pf_load(Yn, pf);
    }
    // vconv(k) + running argmax on sigmaY
    {
      float a4[4] = {0,0,0,0}, b4[4] = {0,0,0,0}, d4[4] = {0,0,0,0};
      #pragma unroll
      for (int j = 0; j < 14; ++j) {
        float ha = hA[y0+j][tx];
        float hb = hB[y0+j][tx];
        float hc = hC[y0+j][tx];
        #pragma unroll
        for (int i = 0; i < 4; ++i) {
          int t = j - i;
          if (t >= 0 && t <= 10) {
            float w = gw.g[t];
            a4[i] = fmaf(w, ha, a4[i]);
            b4[i] = fmaf(w, hb, b4[i]);
            d4[i] = fmaf(w, hc, d4[i]);
          }
        }
      }
      #pragma unroll
      for (int i = 0; i < 4; ++i) {
        float sigY  = b4[i] - a4[i]*a4[i];
        float sigXY = d4[i] - muX[i]*a4[i];
        bool upd = (k == 0) || (sigY > bestS[i]);  // first-max semantics
        bestS[i]  = upd ? sigY  : bestS[i];
        bestXY[i] = upd ? sigXY : bestXY[i];
      }
    }
    if (k < KK-1) {
      pf_store(pf);          // sY <- Y(k+1); phase-A reads fenced by A/B barrier
      __syncthreads();
    }
  }

  // ---- epilogue: cs for both scale branches, block reduction ----
  float s1 = 0.f, s255 = 0.f;
  #pragma unroll
  for (int i = 0; i < 4; ++i) {
    float num1 = 2.0f * bestXY[i] + C2F;
    float den1 = ((sigX[i] + bestS[i]) + C2F) + EPSF;
    s1 += num1 / den1;
    float num2 = 2.0f * (S2F * bestXY[i]) + C2F;
    float den2 = ((S2F * sigX[i] + S2F * bestS[i]) + C2F) + EPSF;
    s255 += num2 / den2;
  }

  #pragma unroll
  for (int off = 32; off > 0; off >>= 1) {
    s1   += __shfl_down(s1, off);
    s255 += __shfl_down(s255, off);
    vmax  = fmaxf(vmax, __shfl_down(vmax, off));
  }
  int w = tid >> 6;
  if ((tid & 63) == 0) { redf[w] = s1; redf[4+w] = s255; redf[8+w] = vmax; }
  __syncthreads();
  if (tid == 0) {
    float a = redf[0] + redf[1] + redf[2] + redf[3];
    float b = redf[4] + redf[5] + redf[6] + redf[7];
    float m = fmaxf(fmaxf(redf[8], redf[9]), fmaxf(redf[10], redf[11]));
    int bid = (c * NBY + by) * NBX + bx;
    part[bid*4 + 0] = a;
    part[bid*4 + 1] = b;
    part[bid*4 + 2] = m;
  }
}

__global__ __launch_bounds__(256) void mef_reduce(
    const float* __restrict__ part, float* __restrict__ out)
{
  int tid = threadIdx.x;
  double s1 = 0.0, s255 = 0.0;
  float m = 0.f;
  for (int i = tid; i < NBLK; i += 256) {
    s1   += (double)part[i*4 + 0];
    s255 += (double)part[i*4 + 1];
    m     = fmaxf(m, part[i*4 + 2]);
  }
  #pragma unroll
  for (int off = 32; off > 0; off >>= 1) {
    s1   += __shfl_down(s1, off);
    s255 += __shfl_down(s255, off);
    m     = fmaxf(m, __shfl_down(m, off));
  }
  __shared__ double l1[4], l2[4];
  __shared__ float lm[4];
  int w = tid >> 6;
  if ((tid & 63) == 0) { l1[w] = s1; l2[w] = s255; lm[w] = m; }
  __syncthreads();
  if (tid == 0) {
    double a = 0.0, b = 0.0; float mm = 0.f;
    for (int i = 0; i < 4; ++i) { a += l1[i]; b += l2[i]; mm = fmaxf(mm, lm[i]); }
    out[0] = (float)(((mm <= 1.0f) ? b : a) / 3145728.0);
  }
}

extern "C" void kernel_launch(void* const* d_in, const int* in_sizes, int n_in,
                              void* d_out, int out_size, void* d_ws, size_t ws_size,
                              hipStream_t stream) {
  const float* X  = (const float*)d_in[0];
  const float* Ys = (const float*)d_in[1];
  // d_in[2] (window) unused: analytic Gaussian (WS=11, sigma=1.5) rebuilt on host.
  float* part = (float*)d_ws;
  float* out  = (float*)d_out;

  GW gw;
  double gd[11], s = 0.0;
  for (int i = 0; i < 11; ++i) {
    double x = (double)(i - 5);
    gd[i] = exp(-(x*x) / (2.0 * 1.5 * 1.5));
    s += gd[i];
  }
  for (int i = 0; i < 11; ++i) gw.g[i] = (float)(gd[i] / s);

  dim3 grid(NBX, NBY, CCH);
  mef_main<<<grid, dim3(256), 0, stream>>>(X, Ys, part, gw);
  mef_reduce<<<1, dim3(256), 0, stream>>>(part, out);
}